// Round 1
// baseline (9998.036 us; speedup 1.0000x reference)
//
#include <hip/hip_runtime.h>

#define DIM    128
#define HEADS  4
#define CH     32
#define MEMLEN 256
#define LAYERS 4
#define EPB    8   // edges/rows per block in edge-sized kernels

// ---------------- utility ----------------

__global__ void copy_f4(const float4* __restrict__ in, float4* __restrict__ out, long n) {
    long i = (long)blockIdx.x * blockDim.x + threadIdx.x;
    long stride = (long)gridDim.x * blockDim.x;
    for (; i < n; i += stride) out[i] = in[i];
}

__global__ void hist_k(const int* __restrict__ dst, int E, int* __restrict__ deg) {
    int e = blockIdx.x * blockDim.x + threadIdx.x;
    if (e < E) atomicAdd(&deg[dst[e]], 1);
}

// one block, 1024 threads: exclusive scan of deg[0..n) -> off[0..n]
__global__ void csr_offsets(const int* __restrict__ deg, int n, int* __restrict__ off) {
    __shared__ int part[1024];
    int t = threadIdx.x;
    int chunk = (n + 1023) >> 10;
    int lo = t * chunk, hi = min(lo + chunk, n);
    int s = 0;
    for (int i = lo; i < hi; i++) s += deg[i];
    part[t] = s; __syncthreads();
    for (int d = 1; d < 1024; d <<= 1) {
        int v = part[t];
        int add = (t >= d) ? part[t - d] : 0;
        __syncthreads();
        part[t] = v + add;
        __syncthreads();
    }
    int run = (t == 0) ? 0 : part[t - 1];
    for (int i = lo; i < hi; i++) { off[i] = run; run += deg[i]; }
    if (t == 1023) off[n] = part[1023];
}

__global__ void csr_fill(const int* __restrict__ dst, int E, const int* __restrict__ off,
                         int* __restrict__ cur, int* __restrict__ csr) {
    int e = blockIdx.x * blockDim.x + threadIdx.x;
    if (e < E) {
        int d = dst[e];
        int p = atomicAdd(&cur[d], 1);
        csr[off[d] + p] = e;
    }
}

__device__ __forceinline__ float block_reduce_sum128(float v, float* red) {
    int t = threadIdx.x;
    red[t] = v; __syncthreads();
#pragma unroll
    for (int s = 64; s > 0; s >>= 1) {
        if (t < s) red[t] += red[t + s];
        __syncthreads();
    }
    float r = red[0]; __syncthreads();
    return r;
}

// ---------------- layer kernels ----------------

// h = x @ Wn ; epilogue: ssrc[n,h] = h[n]·att_src[h], sdst likewise. 1 row/block, 128 thr.
__global__ void node_proj(const float* __restrict__ x, const float* __restrict__ W,
                          const float* __restrict__ att_s, const float* __restrict__ att_d,
                          float* __restrict__ h, float* __restrict__ ssrc, float* __restrict__ sdst,
                          int N) {
    int n = blockIdx.x, t = threadIdx.x;
    __shared__ float row[DIM];
    row[t] = x[(size_t)n * DIM + t];
    __syncthreads();
    float acc = 0.f;
#pragma unroll 8
    for (int k = 0; k < DIM; k++) acc += row[k] * W[k * DIM + t];
    h[(size_t)n * DIM + t] = acc;
    int lane = t & 31, hh = t >> 5;
    float p = acc * att_s[t];
#pragma unroll
    for (int m = 16; m; m >>= 1) p += __shfl_xor(p, m, 32);
    if (lane == 0) ssrc[n * HEADS + hh] = p;
    float q = acc * att_d[t];
#pragma unroll
    for (int m = 16; m; m >>= 1) q += __shfl_xor(q, m, 32);
    if (lane == 0) sdst[n * HEADS + hh] = q;
}

// eh = e @ We ; epilogue sedge[e,h] = eh·att_edge[h]. EPB rows/block.
__global__ void edge_proj(const float* __restrict__ e, const float* __restrict__ W,
                          const float* __restrict__ att_e,
                          float* __restrict__ eh, float* __restrict__ sedge, int E) {
    int e0 = blockIdx.x * EPB, t = threadIdx.x;
    int ne = min(EPB, E - e0);
    __shared__ float cat[EPB * DIM];
    for (int ee = 0; ee < ne; ee++)
        cat[ee * DIM + t] = e[(size_t)(e0 + ee) * DIM + t];
    __syncthreads();
    float acc[EPB];
#pragma unroll
    for (int ee = 0; ee < EPB; ee++) acc[ee] = 0.f;
    for (int k = 0; k < DIM; k++) {
        float w = W[k * DIM + t];
#pragma unroll
        for (int ee = 0; ee < EPB; ee++) acc[ee] += cat[ee * DIM + k] * w;
    }
    int lane = t & 31, hh = t >> 5;
    float ae = att_e[t];
#pragma unroll
    for (int ee = 0; ee < EPB; ee++) {
        if (ee < ne) {
            eh[(size_t)(e0 + ee) * DIM + t] = acc[ee];
            float p = acc[ee] * ae;
#pragma unroll
            for (int m = 16; m; m >>= 1) p += __shfl_xor(p, m, 32);
            if (lane == 0) sedge[(e0 + ee) * HEADS + hh] = p;
        }
    }
}

__global__ void logits_k(const int* __restrict__ src, const int* __restrict__ dst,
                         const float* __restrict__ ssrc, const float* __restrict__ sdst,
                         const float* __restrict__ sedge, float* __restrict__ lw, int EH) {
    int i = blockIdx.x * blockDim.x + threadIdx.x;
    if (i >= EH) return;
    int e = i >> 2, hh = i & 3;
    float v = ssrc[src[e] * HEADS + hh] + sdst[dst[e] * HEADS + hh] + sedge[i];
    lw[i] = (v >= 0.f) ? v : 0.2f * v;   // leaky_relu 0.2
}

// per (node, head) thread: segment max, exp, sum. lw becomes unnormalized weights.
__global__ void seg_softmax(const int* __restrict__ off, const int* __restrict__ csr,
                            float* __restrict__ lw, float* __restrict__ den, int NH) {
    int i = blockIdx.x * blockDim.x + threadIdx.x;
    if (i >= NH) return;
    int n = i >> 2, hh = i & 3;
    int o0 = off[n], o1 = off[n + 1];
    float m = -1e30f;
    for (int o = o0; o < o1; o++) m = fmaxf(m, lw[csr[o] * HEADS + hh]);
    float s = 0.f;
    for (int o = o0; o < o1; o++) {
        int idx = csr[o] * HEADS + hh;
        float w = __expf(lw[idx] - m);
        lw[idx] = w;
        s += w;
    }
    den[i] = s;
}

// conv gather + bn + LN1 + relu + residual, in-place on x. 1 node/block, 128 thr.
__global__ void conv_ln(const int* __restrict__ off, const int* __restrict__ csr,
                        const int* __restrict__ src,
                        const float* __restrict__ lw, const float* __restrict__ den,
                        const float* __restrict__ hbuf, const float* __restrict__ ehbuf,
                        const float* __restrict__ bn, const float* __restrict__ g,
                        const float* __restrict__ b, float* __restrict__ x, int N) {
    int n = blockIdx.x, t = threadIdx.x, hh = t >> 5;
    __shared__ float red[DIM];
    int o0 = off[n], o1 = off[n + 1];
    float acc = 0.f;
    for (int o = o0; o < o1; o++) {
        int e = csr[o];
        int s = src[e];
        float w = lw[e * HEADS + hh];
        acc += w * (hbuf[(size_t)s * DIM + t] + ehbuf[(size_t)e * DIM + t]);
    }
    float d = den[n * HEADS + hh];
    acc = acc / (d + 1e-16f) + bn[t];
    float mu = block_reduce_sum128(acc, red) * (1.f / DIM);
    float diff = acc - mu;
    float var = block_reduce_sum128(diff * diff, red) * (1.f / DIM);
    float y = diff * rsqrtf(var + 1e-5f) * g[t] + b[t];
    x[(size_t)n * DIM + t] = fmaxf(y, 0.f) + x[(size_t)n * DIM + t];
}

// k = memory @ Wk, v = memory @ Wv. 1 row/block.
__global__ void kv_proj(const float* __restrict__ mem, const float* __restrict__ Wk,
                        const float* __restrict__ Wv, float* __restrict__ kb,
                        float* __restrict__ vb, int R) {
    int r = blockIdx.x, t = threadIdx.x;
    __shared__ float row[DIM];
    row[t] = mem[(size_t)r * DIM + t];
    __syncthreads();
    float ak = 0.f, av = 0.f;
#pragma unroll 4
    for (int k = 0; k < DIM; k++) {
        float rv = row[k];
        ak += rv * Wk[k * DIM + t];
        av += rv * Wv[k * DIM + t];
    }
    kb[(size_t)r * DIM + t] = ak;
    vb[(size_t)r * DIM + t] = av;
}

// fused q-proj + cross attention + Wo + LN2 + relu, in-place on x. 1 node/block.
__global__ void cross_attn(float* __restrict__ x, const int* __restrict__ n2b,
                           const float* __restrict__ kb, const float* __restrict__ vb,
                           const float* __restrict__ Wq, const float* __restrict__ Wo,
                           const float* __restrict__ g, const float* __restrict__ b, int N) {
    int n = blockIdx.x, t = threadIdx.x;
    int hh = t >> 5, lane = t & 31;
    __shared__ float row[DIM], qv[DIM], p[HEADS * MEMLEN], ao[DIM], red[DIM];
    row[t] = x[(size_t)n * DIM + t];
    __syncthreads();
    float acc = 0.f;
#pragma unroll 8
    for (int k = 0; k < DIM; k++) acc += row[k] * Wq[k * DIM + t];
    qv[t] = acc;
    __syncthreads();
    int bb = n2b[n];
    const float* Kb = kb + (size_t)bb * MEMLEN * DIM;
    const float* Vb = vb + (size_t)bb * MEMLEN * DIM;
    float sloc[MEMLEN / 32];
    float smax = -1e30f;
#pragma unroll
    for (int j = 0; j < MEMLEN / 32; j++) {
        int key = lane + j * 32;
        const float* kr = Kb + (size_t)key * DIM + hh * CH;
        float s = 0.f;
#pragma unroll
        for (int c = 0; c < CH; c++) s += qv[hh * CH + c] * kr[c];
        s *= 0.17677669529663689f;   // 1/sqrt(32)
        sloc[j] = s;
        smax = fmaxf(smax, s);
    }
#pragma unroll
    for (int m = 16; m; m >>= 1) smax = fmaxf(smax, __shfl_xor(smax, m, 32));
    float lsum = 0.f;
#pragma unroll
    for (int j = 0; j < MEMLEN / 32; j++) {
        float w = __expf(sloc[j] - smax);
        p[hh * MEMLEN + lane + j * 32] = w;
        lsum += w;
    }
#pragma unroll
    for (int m = 16; m; m >>= 1) lsum += __shfl_xor(lsum, m, 32);
    __syncthreads();
    float av = 0.f;
    for (int j = 0; j < MEMLEN; j++)
        av += p[hh * MEMLEN + j] * Vb[(size_t)j * DIM + hh * CH + lane];
    av /= lsum;
    ao[t] = av;
    __syncthreads();
    float o = 0.f;
#pragma unroll 8
    for (int k = 0; k < DIM; k++) o += ao[k] * Wo[k * DIM + t];
    o += row[t];
    float mu = block_reduce_sum128(o, red) * (1.f / DIM);
    float diff = o - mu;
    float var = block_reduce_sum128(diff * diff, red) * (1.f / DIM);
    float y = diff * rsqrtf(var + 1e-5f) * g[t] + b[t];
    x[(size_t)n * DIM + t] = fmaxf(y, 0.f);
}

// e += relu([e, x_src, x_dst] @ Ew1 + Eb1) @ Ew2 + Eb2. EPB edges/block.
__global__ void edge_mlp(float* __restrict__ e, const float* __restrict__ x,
                         const int* __restrict__ src, const int* __restrict__ dst,
                         const float* __restrict__ Ew1, const float* __restrict__ Eb1,
                         const float* __restrict__ Ew2, const float* __restrict__ Eb2, int E) {
    int e0 = blockIdx.x * EPB, t = threadIdx.x;
    int ne = min(EPB, E - e0);
    __shared__ float cat[EPB * 3 * DIM];
    __shared__ float hid[EPB * DIM];
    for (int ee = 0; ee < ne; ee++) {
        int eid = e0 + ee;
        cat[ee * 3 * DIM + t]           = e[(size_t)eid * DIM + t];
        cat[ee * 3 * DIM + DIM + t]     = x[(size_t)src[eid] * DIM + t];
        cat[ee * 3 * DIM + 2 * DIM + t] = x[(size_t)dst[eid] * DIM + t];
    }
    __syncthreads();
    float a[EPB];
    float b1 = Eb1[t];
#pragma unroll
    for (int ee = 0; ee < EPB; ee++) a[ee] = b1;
    for (int k = 0; k < 3 * DIM; k++) {
        float w = Ew1[(size_t)k * DIM + t];
#pragma unroll
        for (int ee = 0; ee < EPB; ee++) a[ee] += cat[ee * 3 * DIM + k] * w;
    }
#pragma unroll
    for (int ee = 0; ee < EPB; ee++) hid[ee * DIM + t] = fmaxf(a[ee], 0.f);
    __syncthreads();
    float o[EPB];
    float b2 = Eb2[t];
#pragma unroll
    for (int ee = 0; ee < EPB; ee++) o[ee] = b2;
    for (int k = 0; k < DIM; k++) {
        float w = Ew2[k * DIM + t];
#pragma unroll
        for (int ee = 0; ee < EPB; ee++) o[ee] += hid[ee * DIM + k] * w;
    }
#pragma unroll
    for (int ee = 0; ee < EPB; ee++) {
        if (ee < ne) e[(size_t)(e0 + ee) * DIM + t] += o[ee];
    }
}

// ---------------- driver ----------------

extern "C" void kernel_launch(void* const* d_in, const int* in_sizes, int n_in,
                              void* d_out, int out_size, void* d_ws, size_t ws_size,
                              hipStream_t stream) {
    const float* node_feats = (const float*)d_in[0];
    const float* edge_feats = (const float*)d_in[1];
    const float* memory     = (const float*)d_in[2];
    const float* Wn   = (const float*)d_in[3];
    const float* bn   = (const float*)d_in[4];
    const float* We   = (const float*)d_in[5];
    const float* att_src  = (const float*)d_in[6];
    const float* att_dst  = (const float*)d_in[7];
    const float* att_edge = (const float*)d_in[8];
    const float* ln1_g = (const float*)d_in[9];
    const float* ln1_b = (const float*)d_in[10];
    const float* ln2_g = (const float*)d_in[11];
    const float* ln2_b = (const float*)d_in[12];
    const float* Wq = (const float*)d_in[13];
    const float* Wk = (const float*)d_in[14];
    const float* Wv = (const float*)d_in[15];
    const float* Wo = (const float*)d_in[16];
    const float* Ew1 = (const float*)d_in[17];
    const float* Eb1 = (const float*)d_in[18];
    const float* Ew2 = (const float*)d_in[19];
    const float* Eb2 = (const float*)d_in[20];
    const int* edge_index = (const int*)d_in[21];
    const int* node2batch = (const int*)d_in[22];

    const int N = in_sizes[0] / DIM;
    const int E = in_sizes[1] / DIM;
    const int Bn = in_sizes[2] / (MEMLEN * DIM);
    const int* srcA = edge_index;
    const int* dstA = edge_index + E;

    float* x = (float*)d_out;
    float* e = x + (size_t)N * DIM;

    // workspace carve
    char* p = (char*)d_ws;
    auto carve = [&](size_t bytes) {
        void* r = (void*)p;
        p += (bytes + 255) & ~(size_t)255;
        return r;
    };
    float* h     = (float*)carve((size_t)N * DIM * 4);
    float* eh    = (float*)carve((size_t)E * DIM * 4);
    float* ssrc  = (float*)carve((size_t)N * HEADS * 4);
    float* sdst  = (float*)carve((size_t)N * HEADS * 4);
    float* sedge = (float*)carve((size_t)E * HEADS * 4);
    float* lw    = (float*)carve((size_t)E * HEADS * 4);
    float* den   = (float*)carve((size_t)N * HEADS * 4);
    float* kbuf  = (float*)carve((size_t)Bn * MEMLEN * DIM * 4);
    float* vbuf  = (float*)carve((size_t)Bn * MEMLEN * DIM * 4);
    int* deg     = (int*)carve((size_t)N * 4);
    int* cur     = (int*)carve((size_t)N * 4);
    int* off     = (int*)carve(((size_t)N + 1) * 4);
    int* csr     = (int*)carve((size_t)E * 4);

    // init outputs from inputs
    {
        long nx = (long)N * DIM / 4;
        copy_f4<<<dim3(2048), dim3(256), 0, stream>>>((const float4*)node_feats, (float4*)x, nx);
        long nen = (long)E * DIM / 4;
        copy_f4<<<dim3(4096), dim3(256), 0, stream>>>((const float4*)edge_feats, (float4*)e, nen);
    }

    // CSR over dst
    hipMemsetAsync(deg, 0, (size_t)N * 4, stream);
    hipMemsetAsync(cur, 0, (size_t)N * 4, stream);
    hist_k<<<dim3((E + 255) / 256), dim3(256), 0, stream>>>(dstA, E, deg);
    csr_offsets<<<dim3(1), dim3(1024), 0, stream>>>(deg, N, off);
    csr_fill<<<dim3((E + 255) / 256), dim3(256), 0, stream>>>(dstA, E, off, cur, csr);

    const int mrows = Bn * MEMLEN;
    for (int l = 0; l < LAYERS; l++) {
        const float* Wn_l  = Wn  + (size_t)l * DIM * DIM;
        const float* We_l  = We  + (size_t)l * DIM * DIM;
        const float* Wq_l  = Wq  + (size_t)l * DIM * DIM;
        const float* Wk_l  = Wk  + (size_t)l * DIM * DIM;
        const float* Wv_l  = Wv  + (size_t)l * DIM * DIM;
        const float* Wo_l  = Wo  + (size_t)l * DIM * DIM;
        const float* Ew1_l = Ew1 + (size_t)l * 3 * DIM * DIM;
        const float* Ew2_l = Ew2 + (size_t)l * DIM * DIM;

        node_proj<<<dim3(N), dim3(DIM), 0, stream>>>(
            x, Wn_l, att_src + l * DIM, att_dst + l * DIM, h, ssrc, sdst, N);
        edge_proj<<<dim3((E + EPB - 1) / EPB), dim3(DIM), 0, stream>>>(
            e, We_l, att_edge + l * DIM, eh, sedge, E);
        logits_k<<<dim3((E * HEADS + 255) / 256), dim3(256), 0, stream>>>(
            srcA, dstA, ssrc, sdst, sedge, lw, E * HEADS);
        seg_softmax<<<dim3((N * HEADS + 255) / 256), dim3(256), 0, stream>>>(
            off, csr, lw, den, N * HEADS);
        conv_ln<<<dim3(N), dim3(DIM), 0, stream>>>(
            off, csr, srcA, lw, den, h, eh, bn + l * DIM, ln1_g + l * DIM, ln1_b + l * DIM, x, N);
        kv_proj<<<dim3(mrows), dim3(DIM), 0, stream>>>(
            memory, Wk_l, Wv_l, kbuf, vbuf, mrows);
        cross_attn<<<dim3(N), dim3(DIM), 0, stream>>>(
            x, node2batch, kbuf, vbuf, Wq_l, Wo_l, ln2_g + l * DIM, ln2_b + l * DIM, N);
        edge_mlp<<<dim3((E + EPB - 1) / EPB), dim3(DIM), 0, stream>>>(
            e, x, srcA, dstA, Ew1_l, Eb1 + l * DIM, Ew2_l, Eb2 + l * DIM, E);
    }
}

// Round 2
// 6208.813 us; speedup vs baseline: 1.6103x; 1.6103x over previous
//
#include <hip/hip_runtime.h>

#define DIM    128
#define HEADS  4
#define CH     32
#define MEMLEN 256
#define LAYERS 4

// ---------------- utility ----------------

__global__ void copy_f4(const float4* __restrict__ in, float4* __restrict__ out, long n) {
    long i = (long)blockIdx.x * blockDim.x + threadIdx.x;
    long stride = (long)gridDim.x * blockDim.x;
    for (; i < n; i += stride) out[i] = in[i];
}

__global__ void hist_k(const int* __restrict__ dst, int E, int* __restrict__ deg) {
    int e = blockIdx.x * blockDim.x + threadIdx.x;
    if (e < E) atomicAdd(&deg[dst[e]], 1);
}

// one block, 1024 threads: exclusive scan of deg[0..n) -> off[0..n]
__global__ void csr_offsets(const int* __restrict__ deg, int n, int* __restrict__ off) {
    __shared__ int part[1024];
    int t = threadIdx.x;
    int chunk = (n + 1023) >> 10;
    int lo = t * chunk, hi = min(lo + chunk, n);
    int s = 0;
    for (int i = lo; i < hi; i++) s += deg[i];
    part[t] = s; __syncthreads();
    for (int d = 1; d < 1024; d <<= 1) {
        int v = part[t];
        int add = (t >= d) ? part[t - d] : 0;
        __syncthreads();
        part[t] = v + add;
        __syncthreads();
    }
    int run = (t == 0) ? 0 : part[t - 1];
    for (int i = lo; i < hi; i++) { off[i] = run; run += deg[i]; }
    if (t == 1023) off[n] = part[1023];
}

__global__ void csr_fill(const int* __restrict__ dst, int E, const int* __restrict__ off,
                         int* __restrict__ cur, int* __restrict__ csr) {
    int e = blockIdx.x * blockDim.x + threadIdx.x;
    if (e < E) {
        int d = dst[e];
        int p = atomicAdd(&cur[d], 1);
        csr[off[d] + p] = e;
    }
}

__device__ __forceinline__ float block_reduce_sum128(float v, float* red) {
    int t = threadIdx.x;
    red[t] = v; __syncthreads();
#pragma unroll
    for (int s = 64; s > 0; s >>= 1) {
        if (t < s) red[t] += red[t + s];
        __syncthreads();
    }
    float r = red[0]; __syncthreads();
    return r;
}

// ---------------- generic 64x128 fp32 tile GEMM: out = A@W (+bias) ----------------
// A [R][128], W [128][128], out [R][128]. 256 threads, 8 rows x 4 cols per thread.
__global__ __launch_bounds__(256) void gemm128(const float* __restrict__ A,
                                               const float* __restrict__ W,
                                               const float* __restrict__ bias,
                                               float* __restrict__ out, int R) {
    int r0 = blockIdx.x * 64, t = threadIdx.x;
    __shared__ float at[64][DIM];
    for (int i = t; i < 64 * 32; i += 256) {
        int rr = i >> 5, cc = i & 31;
        if (r0 + rr < R)
            ((float4*)at[rr])[cc] = ((const float4*)(A + (size_t)(r0 + rr) * DIM))[cc];
    }
    __syncthreads();
    int c0 = (t & 31) * 4;
    int rb = (t >> 5) * 8;
    float acc[8][4];
#pragma unroll
    for (int ee = 0; ee < 8; ee++)
        acc[ee][0] = acc[ee][1] = acc[ee][2] = acc[ee][3] = 0.f;
    for (int k = 0; k < DIM; k += 4) {
        float4 w0 = *(const float4*)&W[(k + 0) * DIM + c0];
        float4 w1 = *(const float4*)&W[(k + 1) * DIM + c0];
        float4 w2 = *(const float4*)&W[(k + 2) * DIM + c0];
        float4 w3 = *(const float4*)&W[(k + 3) * DIM + c0];
#pragma unroll
        for (int ee = 0; ee < 8; ee++) {
            float4 a = *(float4*)&at[rb + ee][k];
            acc[ee][0] += a.x * w0.x + a.y * w1.x + a.z * w2.x + a.w * w3.x;
            acc[ee][1] += a.x * w0.y + a.y * w1.y + a.z * w2.y + a.w * w3.y;
            acc[ee][2] += a.x * w0.z + a.y * w1.z + a.z * w2.z + a.w * w3.z;
            acc[ee][3] += a.x * w0.w + a.y * w1.w + a.z * w2.w + a.w * w3.w;
        }
    }
    float4 bb = make_float4(0.f, 0.f, 0.f, 0.f);
    if (bias) bb = *(const float4*)&bias[c0];
#pragma unroll
    for (int ee = 0; ee < 8; ee++) {
        int r = r0 + rb + ee;
        if (r < R) {
            float4 o = make_float4(acc[ee][0] + bb.x, acc[ee][1] + bb.y,
                                   acc[ee][2] + bb.z, acc[ee][3] + bb.w);
            *(float4*)&out[(size_t)r * DIM + c0] = o;
        }
    }
}

// ---------------- layer kernels ----------------

// h = x @ Wn ; epilogue: ssrc[n,h] = h[n]·att_src[h], sdst likewise. 1 row/block, 128 thr.
__global__ void node_proj(const float* __restrict__ x, const float* __restrict__ W,
                          const float* __restrict__ att_s, const float* __restrict__ att_d,
                          float* __restrict__ h, float* __restrict__ ssrc, float* __restrict__ sdst,
                          int N) {
    int n = blockIdx.x, t = threadIdx.x;
    __shared__ float row[DIM];
    row[t] = x[(size_t)n * DIM + t];
    __syncthreads();
    float acc = 0.f;
#pragma unroll 8
    for (int k = 0; k < DIM; k++) acc += row[k] * W[k * DIM + t];
    h[(size_t)n * DIM + t] = acc;
    int lane = t & 31, hh = t >> 5;
    float p = acc * att_s[t];
#pragma unroll
    for (int m = 16; m; m >>= 1) p += __shfl_xor(p, m, 32);
    if (lane == 0) ssrc[n * HEADS + hh] = p;
    float q = acc * att_d[t];
#pragma unroll
    for (int m = 16; m; m >>= 1) q += __shfl_xor(q, m, 32);
    if (lane == 0) sdst[n * HEADS + hh] = q;
}

// waE[k][h] = sum_c We[k][h*32+c] * att_edge[h*32+c]   (1 block, 128 threads)
__global__ void make_waE(const float* __restrict__ We, const float* __restrict__ att_e,
                         float* __restrict__ waE) {
    int k = threadIdx.x;
#pragma unroll
    for (int h = 0; h < HEADS; h++) {
        float s = 0.f;
#pragma unroll
        for (int c = 0; c < CH; c++) s += We[k * DIM + h * CH + c] * att_e[h * CH + c];
        waE[k * HEADS + h] = s;
    }
}

// lw[e,h] = leaky(ssrc[src,h] + sdst[dst,h] + e_row · waE[:,h]).  8 edges/block, 256 thr.
__global__ void sedge_logits(const float* __restrict__ e, const float* __restrict__ waE,
                             const float* __restrict__ ssrc, const float* __restrict__ sdst,
                             const int* __restrict__ src, const int* __restrict__ dst,
                             float* __restrict__ lw, int E) {
    __shared__ float w[DIM * HEADS];
    int t = threadIdx.x;
    w[t] = waE[t]; w[t + 256] = waE[t + 256];
    __syncthreads();
    int g = t >> 5, lane = t & 31;
    int eid = blockIdx.x * 8 + g;
    if (eid >= E) return;
    const float* er = e + (size_t)eid * DIM;
    float s0 = 0.f, s1 = 0.f, s2 = 0.f, s3 = 0.f;
#pragma unroll
    for (int j = 0; j < 4; j++) {
        int k = lane + 32 * j;
        float v = er[k];
        s0 += v * w[k * 4 + 0]; s1 += v * w[k * 4 + 1];
        s2 += v * w[k * 4 + 2]; s3 += v * w[k * 4 + 3];
    }
#pragma unroll
    for (int m = 16; m; m >>= 1) {
        s0 += __shfl_xor(s0, m, 32); s1 += __shfl_xor(s1, m, 32);
        s2 += __shfl_xor(s2, m, 32); s3 += __shfl_xor(s3, m, 32);
    }
    if (lane == 0) {
        int sn = src[eid] * HEADS, dn = dst[eid] * HEADS;
        float l0 = ssrc[sn + 0] + sdst[dn + 0] + s0;
        float l1 = ssrc[sn + 1] + sdst[dn + 1] + s1;
        float l2 = ssrc[sn + 2] + sdst[dn + 2] + s2;
        float l3 = ssrc[sn + 3] + sdst[dn + 3] + s3;
        lw[eid * 4 + 0] = (l0 >= 0.f) ? l0 : 0.2f * l0;
        lw[eid * 4 + 1] = (l1 >= 0.f) ? l1 : 0.2f * l1;
        lw[eid * 4 + 2] = (l2 >= 0.f) ? l2 : 0.2f * l2;
        lw[eid * 4 + 3] = (l3 >= 0.f) ? l3 : 0.2f * l3;
    }
}

// per (node, head) thread: segment max, exp, sum. lw becomes unnormalized weights.
__global__ void seg_softmax(const int* __restrict__ off, const int* __restrict__ csr,
                            float* __restrict__ lw, float* __restrict__ den, int NH) {
    int i = blockIdx.x * blockDim.x + threadIdx.x;
    if (i >= NH) return;
    int n = i >> 2, hh = i & 3;
    int o0 = off[n], o1 = off[n + 1];
    float m = -1e30f;
    for (int o = o0; o < o1; o++) m = fmaxf(m, lw[csr[o] * HEADS + hh]);
    float s = 0.f;
    for (int o = o0; o < o1; o++) {
        int idx = csr[o] * HEADS + hh;
        float w = __expf(lw[idx] - m);
        lw[idx] = w;
        s += w;
    }
    den[i] = s;
}

// conv gather: agg_h = sum ew*h[src]; agg_e[h] = sum ew_h * e_row; then
// conv = (agg_h + agg_e[hh]@We[:,col]) / den + bn; LN1; relu; residual. 1 node/block.
__global__ void conv_ln(const int* __restrict__ off, const int* __restrict__ csr,
                        const int* __restrict__ src,
                        const float* __restrict__ lw, const float* __restrict__ den,
                        const float* __restrict__ hbuf, const float* __restrict__ e,
                        const float* __restrict__ We,
                        const float* __restrict__ bn, const float* __restrict__ g,
                        const float* __restrict__ b, float* __restrict__ x, int N) {
    int n = blockIdx.x, t = threadIdx.x, hh = t >> 5;
    __shared__ float agge[HEADS][DIM];
    __shared__ float red[DIM];
    int o0 = off[n], o1 = off[n + 1];
    float acch = 0.f, a0 = 0.f, a1 = 0.f, a2 = 0.f, a3 = 0.f;
    for (int o = o0; o < o1; o++) {
        int eid = csr[o];
        int s = src[eid];
        float4 al = *(const float4*)&lw[eid * 4];
        acch += ((&al.x)[hh]) * hbuf[(size_t)s * DIM + t];
        float ev = e[(size_t)eid * DIM + t];
        a0 += al.x * ev; a1 += al.y * ev; a2 += al.z * ev; a3 += al.w * ev;
    }
    agge[0][t] = a0; agge[1][t] = a1; agge[2][t] = a2; agge[3][t] = a3;
    __syncthreads();
    float ehc = 0.f;
#pragma unroll 8
    for (int k = 0; k < DIM; k++) ehc += agge[hh][k] * We[k * DIM + t];
    float d = den[n * HEADS + hh];
    float conv = (acch + ehc) / (d + 1e-16f) + bn[t];
    float mu = block_reduce_sum128(conv, red) * (1.f / DIM);
    float diff = conv - mu;
    float var = block_reduce_sum128(diff * diff, red) * (1.f / DIM);
    float y = diff * rsqrtf(var + 1e-5f) * g[t] + b[t];
    x[(size_t)n * DIM + t] = fmaxf(y, 0.f) + x[(size_t)n * DIM + t];
}

// k = memory @ Wk, v = memory @ Wv. 1 row/block.
__global__ void kv_proj(const float* __restrict__ mem, const float* __restrict__ Wk,
                        const float* __restrict__ Wv, float* __restrict__ kb,
                        float* __restrict__ vb, int R) {
    int r = blockIdx.x, t = threadIdx.x;
    __shared__ float row[DIM];
    row[t] = mem[(size_t)r * DIM + t];
    __syncthreads();
    float ak = 0.f, av = 0.f;
#pragma unroll 4
    for (int k = 0; k < DIM; k++) {
        float rv = row[k];
        ak += rv * Wk[k * DIM + t];
        av += rv * Wv[k * DIM + t];
    }
    kb[(size_t)r * DIM + t] = ak;
    vb[(size_t)r * DIM + t] = av;
}

// fused q-proj + cross attention + Wo + LN2 + relu, in-place on x. 1 node/block.
__global__ void cross_attn(float* __restrict__ x, const int* __restrict__ n2b,
                           const float* __restrict__ kb, const float* __restrict__ vb,
                           const float* __restrict__ Wq, const float* __restrict__ Wo,
                           const float* __restrict__ g, const float* __restrict__ b, int N) {
    int n = blockIdx.x, t = threadIdx.x;
    int hh = t >> 5, lane = t & 31;
    __shared__ float row[DIM], qv[DIM], p[HEADS * MEMLEN], ao[DIM], red[DIM];
    row[t] = x[(size_t)n * DIM + t];
    __syncthreads();
    float acc = 0.f;
#pragma unroll 8
    for (int k = 0; k < DIM; k++) acc += row[k] * Wq[k * DIM + t];
    qv[t] = acc;
    __syncthreads();
    int bb = n2b[n];
    const float* Kb = kb + (size_t)bb * MEMLEN * DIM;
    const float* Vb = vb + (size_t)bb * MEMLEN * DIM;
    float sloc[MEMLEN / 32];
    float smax = -1e30f;
#pragma unroll
    for (int j = 0; j < MEMLEN / 32; j++) {
        int key = lane + j * 32;
        const float* kr = Kb + (size_t)key * DIM + hh * CH;
        float s = 0.f;
#pragma unroll
        for (int c = 0; c < CH; c++) s += qv[hh * CH + c] * kr[c];
        s *= 0.17677669529663689f;   // 1/sqrt(32)
        sloc[j] = s;
        smax = fmaxf(smax, s);
    }
#pragma unroll
    for (int m = 16; m; m >>= 1) smax = fmaxf(smax, __shfl_xor(smax, m, 32));
    float lsum = 0.f;
#pragma unroll
    for (int j = 0; j < MEMLEN / 32; j++) {
        float w = __expf(sloc[j] - smax);
        p[hh * MEMLEN + lane + j * 32] = w;
        lsum += w;
    }
#pragma unroll
    for (int m = 16; m; m >>= 1) lsum += __shfl_xor(lsum, m, 32);
    __syncthreads();
    float av = 0.f;
    for (int j = 0; j < MEMLEN; j++)
        av += p[hh * MEMLEN + j] * Vb[(size_t)j * DIM + hh * CH + lane];
    av /= lsum;
    ao[t] = av;
    __syncthreads();
    float o = 0.f;
#pragma unroll 8
    for (int k = 0; k < DIM; k++) o += ao[k] * Wo[k * DIM + t];
    o += row[t];
    float mu = block_reduce_sum128(o, red) * (1.f / DIM);
    float diff = o - mu;
    float var = block_reduce_sum128(diff * diff, red) * (1.f / DIM);
    float y = diff * rsqrtf(var + 1e-5f) * g[t] + b[t];
    x[(size_t)n * DIM + t] = fmaxf(y, 0.f);
}

// hid = relu(e@W1 + xs[src] + xd[dst]); e += hid@W2 + Eb2.  64 edges/block, 256 thr.
__global__ __launch_bounds__(256) void edge_mlp(float* __restrict__ e,
                                                const float* __restrict__ xs,
                                                const float* __restrict__ xd,
                                                const int* __restrict__ src,
                                                const int* __restrict__ dst,
                                                const float* __restrict__ W1,
                                                const float* __restrict__ W2,
                                                const float* __restrict__ Eb2, int E) {
    int e0 = blockIdx.x * 64, t = threadIdx.x;
    __shared__ float at[64][DIM];
    for (int i = t; i < 64 * 32; i += 256) {
        int rr = i >> 5, cc = i & 31;
        if (e0 + rr < E)
            ((float4*)at[rr])[cc] = ((const float4*)(e + (size_t)(e0 + rr) * DIM))[cc];
    }
    __syncthreads();
    int c0 = (t & 31) * 4;
    int rb = (t >> 5) * 8;
    float acc[8][4];
#pragma unroll
    for (int ee = 0; ee < 8; ee++)
        acc[ee][0] = acc[ee][1] = acc[ee][2] = acc[ee][3] = 0.f;
    for (int k = 0; k < DIM; k += 4) {
        float4 w0 = *(const float4*)&W1[(k + 0) * DIM + c0];
        float4 w1 = *(const float4*)&W1[(k + 1) * DIM + c0];
        float4 w2 = *(const float4*)&W1[(k + 2) * DIM + c0];
        float4 w3 = *(const float4*)&W1[(k + 3) * DIM + c0];
#pragma unroll
        for (int ee = 0; ee < 8; ee++) {
            float4 a = *(float4*)&at[rb + ee][k];
            acc[ee][0] += a.x * w0.x + a.y * w1.x + a.z * w2.x + a.w * w3.x;
            acc[ee][1] += a.x * w0.y + a.y * w1.y + a.z * w2.y + a.w * w3.y;
            acc[ee][2] += a.x * w0.z + a.y * w1.z + a.z * w2.z + a.w * w3.z;
            acc[ee][3] += a.x * w0.w + a.y * w1.w + a.z * w2.w + a.w * w3.w;
        }
    }
#pragma unroll
    for (int ee = 0; ee < 8; ee++) {
        int r = e0 + rb + ee;
        if (r < E) {
            float4 s4 = *(const float4*)&xs[(size_t)src[r] * DIM + c0];
            float4 d4 = *(const float4*)&xd[(size_t)dst[r] * DIM + c0];
            acc[ee][0] = fmaxf(acc[ee][0] + s4.x + d4.x, 0.f);
            acc[ee][1] = fmaxf(acc[ee][1] + s4.y + d4.y, 0.f);
            acc[ee][2] = fmaxf(acc[ee][2] + s4.z + d4.z, 0.f);
            acc[ee][3] = fmaxf(acc[ee][3] + s4.w + d4.w, 0.f);
        }
    }
    __syncthreads();
#pragma unroll
    for (int ee = 0; ee < 8; ee++)
        *(float4*)&at[rb + ee][c0] = make_float4(acc[ee][0], acc[ee][1], acc[ee][2], acc[ee][3]);
    __syncthreads();
#pragma unroll
    for (int ee = 0; ee < 8; ee++)
        acc[ee][0] = acc[ee][1] = acc[ee][2] = acc[ee][3] = 0.f;
    for (int k = 0; k < DIM; k += 4) {
        float4 w0 = *(const float4*)&W2[(k + 0) * DIM + c0];
        float4 w1 = *(const float4*)&W2[(k + 1) * DIM + c0];
        float4 w2 = *(const float4*)&W2[(k + 2) * DIM + c0];
        float4 w3 = *(const float4*)&W2[(k + 3) * DIM + c0];
#pragma unroll
        for (int ee = 0; ee < 8; ee++) {
            float4 a = *(float4*)&at[rb + ee][k];
            acc[ee][0] += a.x * w0.x + a.y * w1.x + a.z * w2.x + a.w * w3.x;
            acc[ee][1] += a.x * w0.y + a.y * w1.y + a.z * w2.y + a.w * w3.y;
            acc[ee][2] += a.x * w0.z + a.y * w1.z + a.z * w2.z + a.w * w3.z;
            acc[ee][3] += a.x * w0.w + a.y * w1.w + a.z * w2.w + a.w * w3.w;
        }
    }
    float4 b2 = *(const float4*)&Eb2[c0];
#pragma unroll
    for (int ee = 0; ee < 8; ee++) {
        int r = e0 + rb + ee;
        if (r < E) {
            float4 old = *(const float4*)&e[(size_t)r * DIM + c0];
            float4 o = make_float4(old.x + acc[ee][0] + b2.x, old.y + acc[ee][1] + b2.y,
                                   old.z + acc[ee][2] + b2.z, old.w + acc[ee][3] + b2.w);
            *(float4*)&e[(size_t)r * DIM + c0] = o;
        }
    }
}

// ---------------- driver ----------------

extern "C" void kernel_launch(void* const* d_in, const int* in_sizes, int n_in,
                              void* d_out, int out_size, void* d_ws, size_t ws_size,
                              hipStream_t stream) {
    const float* node_feats = (const float*)d_in[0];
    const float* edge_feats = (const float*)d_in[1];
    const float* memory     = (const float*)d_in[2];
    const float* Wn   = (const float*)d_in[3];
    const float* bn   = (const float*)d_in[4];
    const float* We   = (const float*)d_in[5];
    const float* att_src  = (const float*)d_in[6];
    const float* att_dst  = (const float*)d_in[7];
    const float* att_edge = (const float*)d_in[8];
    const float* ln1_g = (const float*)d_in[9];
    const float* ln1_b = (const float*)d_in[10];
    const float* ln2_g = (const float*)d_in[11];
    const float* ln2_b = (const float*)d_in[12];
    const float* Wq = (const float*)d_in[13];
    const float* Wk = (const float*)d_in[14];
    const float* Wv = (const float*)d_in[15];
    const float* Wo = (const float*)d_in[16];
    const float* Ew1 = (const float*)d_in[17];
    const float* Eb1 = (const float*)d_in[18];
    const float* Ew2 = (const float*)d_in[19];
    const float* Eb2 = (const float*)d_in[20];
    const int* edge_index = (const int*)d_in[21];
    const int* node2batch = (const int*)d_in[22];

    const int N = in_sizes[0] / DIM;
    const int E = in_sizes[1] / DIM;
    const int Bn = in_sizes[2] / (MEMLEN * DIM);
    const int* srcA = edge_index;
    const int* dstA = edge_index + E;

    float* x = (float*)d_out;
    float* e = x + (size_t)N * DIM;

    // workspace carve
    char* p = (char*)d_ws;
    auto carve = [&](size_t bytes) {
        void* r = (void*)p;
        p += (bytes + 255) & ~(size_t)255;
        return r;
    };
    float* h     = (float*)carve((size_t)N * DIM * 4);
    float* xs    = (float*)carve((size_t)N * DIM * 4);
    float* xd    = (float*)carve((size_t)N * DIM * 4);
    float* ssrc  = (float*)carve((size_t)N * HEADS * 4);
    float* sdst  = (float*)carve((size_t)N * HEADS * 4);
    float* lw    = (float*)carve((size_t)E * HEADS * 4);
    float* den   = (float*)carve((size_t)N * HEADS * 4);
    float* waE   = (float*)carve((size_t)DIM * HEADS * 4);
    float* kbuf  = (float*)carve((size_t)Bn * MEMLEN * DIM * 4);
    float* vbuf  = (float*)carve((size_t)Bn * MEMLEN * DIM * 4);
    int* deg     = (int*)carve((size_t)N * 4);
    int* cur     = (int*)carve((size_t)N * 4);
    int* off     = (int*)carve(((size_t)N + 1) * 4);
    int* csr     = (int*)carve((size_t)E * 4);

    // init outputs from inputs
    {
        long nx = (long)N * DIM / 4;
        copy_f4<<<dim3(2048), dim3(256), 0, stream>>>((const float4*)node_feats, (float4*)x, nx);
        long nen = (long)E * DIM / 4;
        copy_f4<<<dim3(4096), dim3(256), 0, stream>>>((const float4*)edge_feats, (float4*)e, nen);
    }

    // CSR over dst
    hipMemsetAsync(deg, 0, (size_t)N * 4, stream);
    hipMemsetAsync(cur, 0, (size_t)N * 4, stream);
    hist_k<<<dim3((E + 255) / 256), dim3(256), 0, stream>>>(dstA, E, deg);
    csr_offsets<<<dim3(1), dim3(1024), 0, stream>>>(deg, N, off);
    csr_fill<<<dim3((E + 255) / 256), dim3(256), 0, stream>>>(dstA, E, off, cur, csr);

    const int mrows = Bn * MEMLEN;
    for (int l = 0; l < LAYERS; l++) {
        const float* Wn_l  = Wn  + (size_t)l * DIM * DIM;
        const float* We_l  = We  + (size_t)l * DIM * DIM;
        const float* Wq_l  = Wq  + (size_t)l * DIM * DIM;
        const float* Wk_l  = Wk  + (size_t)l * DIM * DIM;
        const float* Wv_l  = Wv  + (size_t)l * DIM * DIM;
        const float* Wo_l  = Wo  + (size_t)l * DIM * DIM;
        const float* Ew1_l = Ew1 + (size_t)l * 3 * DIM * DIM;
        const float* Ew2_l = Ew2 + (size_t)l * DIM * DIM;

        node_proj<<<dim3(N), dim3(DIM), 0, stream>>>(
            x, Wn_l, att_src + l * DIM, att_dst + l * DIM, h, ssrc, sdst, N);
        make_waE<<<dim3(1), dim3(DIM), 0, stream>>>(We_l, att_edge + l * DIM, waE);
        sedge_logits<<<dim3((E + 7) / 8), dim3(256), 0, stream>>>(
            e, waE, ssrc, sdst, srcA, dstA, lw, E);
        seg_softmax<<<dim3((N * HEADS + 255) / 256), dim3(256), 0, stream>>>(
            off, csr, lw, den, N * HEADS);
        conv_ln<<<dim3(N), dim3(DIM), 0, stream>>>(
            off, csr, srcA, lw, den, h, e, We_l,
            bn + l * DIM, ln1_g + l * DIM, ln1_b + l * DIM, x, N);
        kv_proj<<<dim3(mrows), dim3(DIM), 0, stream>>>(
            memory, Wk_l, Wv_l, kbuf, vbuf, mrows);
        cross_attn<<<dim3(N), dim3(DIM), 0, stream>>>(
            x, node2batch, kbuf, vbuf, Wq_l, Wo_l, ln2_g + l * DIM, ln2_b + l * DIM, N);
        // xs = x @ Ew1[128:256] + Eb1 ; xd = x @ Ew1[256:384]
        gemm128<<<dim3((N + 63) / 64), dim3(256), 0, stream>>>(
            x, Ew1_l + (size_t)DIM * DIM, Eb1 + l * DIM, xs, N);
        gemm128<<<dim3((N + 63) / 64), dim3(256), 0, stream>>>(
            x, Ew1_l + (size_t)2 * DIM * DIM, nullptr, xd, N);
        edge_mlp<<<dim3((E + 63) / 64), dim3(256), 0, stream>>>(
            e, xs, xd, srcA, dstA, Ew1_l, Ew2_l, Eb2 + l * DIM, E);
    }
}

// Round 3
// 4300.234 us; speedup vs baseline: 2.3250x; 1.4438x over previous
//
#include <hip/hip_runtime.h>

#define DIM    128
#define HEADS  4
#define CH     32
#define MEMLEN 256
#define LAYERS 4

// ---------------- utility ----------------

__global__ void copy_f4(const float4* __restrict__ in, float4* __restrict__ out, long n) {
    long i = (long)blockIdx.x * blockDim.x + threadIdx.x;
    long stride = (long)gridDim.x * blockDim.x;
    for (; i < n; i += stride) out[i] = in[i];
}

__global__ void hist_k(const int* __restrict__ dst, int E, int* __restrict__ deg) {
    int e = blockIdx.x * blockDim.x + threadIdx.x;
    if (e < E) atomicAdd(&deg[dst[e]], 1);
}

// one block, 1024 threads: exclusive scan of deg[0..n) -> off[0..n]
__global__ void csr_offsets(const int* __restrict__ deg, int n, int* __restrict__ off) {
    __shared__ int part[1024];
    int t = threadIdx.x;
    int chunk = (n + 1023) >> 10;
    int lo = t * chunk, hi = min(lo + chunk, n);
    int s = 0;
    for (int i = lo; i < hi; i++) s += deg[i];
    part[t] = s; __syncthreads();
    for (int d = 1; d < 1024; d <<= 1) {
        int v = part[t];
        int add = (t >= d) ? part[t - d] : 0;
        __syncthreads();
        part[t] = v + add;
        __syncthreads();
    }
    int run = (t == 0) ? 0 : part[t - 1];
    for (int i = lo; i < hi; i++) { off[i] = run; run += deg[i]; }
    if (t == 1023) off[n] = part[1023];
}

__global__ void csr_fill(const int* __restrict__ dst, int E, const int* __restrict__ off,
                         int* __restrict__ cur, int* __restrict__ csr) {
    int e = blockIdx.x * blockDim.x + threadIdx.x;
    if (e < E) {
        int d = dst[e];
        int p = atomicAdd(&cur[d], 1);
        csr[off[d] + p] = e;
    }
}

__device__ __forceinline__ float block_reduce_sum128(float v, float* red) {
    int t = threadIdx.x;
    red[t] = v; __syncthreads();
#pragma unroll
    for (int s = 64; s > 0; s >>= 1) {
        if (t < s) red[t] += red[t + s];
        __syncthreads();
    }
    float r = red[0]; __syncthreads();
    return r;
}

// ---------------- generic 64x128 fp32 tile GEMM: out = A@W (+bias) ----------------
__global__ __launch_bounds__(256) void gemm128(const float* __restrict__ A,
                                               const float* __restrict__ W,
                                               const float* __restrict__ bias,
                                               float* __restrict__ out, int R) {
    int r0 = blockIdx.x * 64, t = threadIdx.x;
    __shared__ float at[64][DIM];
    for (int i = t; i < 64 * 32; i += 256) {
        int rr = i >> 5, cc = i & 31;
        if (r0 + rr < R)
            ((float4*)at[rr])[cc] = ((const float4*)(A + (size_t)(r0 + rr) * DIM))[cc];
    }
    __syncthreads();
    int c0 = (t & 31) * 4;
    int rb = (t >> 5) * 8;
    float acc[8][4];
#pragma unroll
    for (int ee = 0; ee < 8; ee++)
        acc[ee][0] = acc[ee][1] = acc[ee][2] = acc[ee][3] = 0.f;
    for (int k = 0; k < DIM; k += 4) {
        float4 w0 = *(const float4*)&W[(k + 0) * DIM + c0];
        float4 w1 = *(const float4*)&W[(k + 1) * DIM + c0];
        float4 w2 = *(const float4*)&W[(k + 2) * DIM + c0];
        float4 w3 = *(const float4*)&W[(k + 3) * DIM + c0];
#pragma unroll
        for (int ee = 0; ee < 8; ee++) {
            float4 a = *(float4*)&at[rb + ee][k];
            acc[ee][0] += a.x * w0.x + a.y * w1.x + a.z * w2.x + a.w * w3.x;
            acc[ee][1] += a.x * w0.y + a.y * w1.y + a.z * w2.y + a.w * w3.y;
            acc[ee][2] += a.x * w0.z + a.y * w1.z + a.z * w2.z + a.w * w3.z;
            acc[ee][3] += a.x * w0.w + a.y * w1.w + a.z * w2.w + a.w * w3.w;
        }
    }
    float4 bb = make_float4(0.f, 0.f, 0.f, 0.f);
    if (bias) bb = *(const float4*)&bias[c0];
#pragma unroll
    for (int ee = 0; ee < 8; ee++) {
        int r = r0 + rb + ee;
        if (r < R) {
            float4 o = make_float4(acc[ee][0] + bb.x, acc[ee][1] + bb.y,
                                   acc[ee][2] + bb.z, acc[ee][3] + bb.w);
            *(float4*)&out[(size_t)r * DIM + c0] = o;
        }
    }
}

// ---------------- node proj tile: h = x@Wn, + per-head att dots ----------------
__global__ __launch_bounds__(256) void node_proj_tile(
    const float* __restrict__ x, const float* __restrict__ W,
    const float* __restrict__ att_s, const float* __restrict__ att_d,
    float* __restrict__ h, float* __restrict__ ssrc, float* __restrict__ sdst, int N) {
    int r0 = blockIdx.x * 64, t = threadIdx.x;
    __shared__ float at[64][DIM];
    for (int i = t; i < 64 * 32; i += 256) {
        int rr = i >> 5, cc = i & 31;
        if (r0 + rr < N)
            ((float4*)at[rr])[cc] = ((const float4*)(x + (size_t)(r0 + rr) * DIM))[cc];
    }
    __syncthreads();
    int c0 = (t & 31) * 4;
    int rb = (t >> 5) * 8;
    float acc[8][4];
#pragma unroll
    for (int ee = 0; ee < 8; ee++)
        acc[ee][0] = acc[ee][1] = acc[ee][2] = acc[ee][3] = 0.f;
    for (int k = 0; k < DIM; k += 4) {
        float4 w0 = *(const float4*)&W[(k + 0) * DIM + c0];
        float4 w1 = *(const float4*)&W[(k + 1) * DIM + c0];
        float4 w2 = *(const float4*)&W[(k + 2) * DIM + c0];
        float4 w3 = *(const float4*)&W[(k + 3) * DIM + c0];
#pragma unroll
        for (int ee = 0; ee < 8; ee++) {
            float4 a = *(float4*)&at[rb + ee][k];
            acc[ee][0] += a.x * w0.x + a.y * w1.x + a.z * w2.x + a.w * w3.x;
            acc[ee][1] += a.x * w0.y + a.y * w1.y + a.z * w2.y + a.w * w3.y;
            acc[ee][2] += a.x * w0.z + a.y * w1.z + a.z * w2.z + a.w * w3.z;
            acc[ee][3] += a.x * w0.w + a.y * w1.w + a.z * w2.w + a.w * w3.w;
        }
    }
    int hh = (t & 31) >> 3;   // head owned by this col range
    float4 as = *(const float4*)&att_s[c0];
    float4 ad = *(const float4*)&att_d[c0];
#pragma unroll
    for (int ee = 0; ee < 8; ee++) {
        int r = r0 + rb + ee;
        if (r < N) {
            *(float4*)&h[(size_t)r * DIM + c0] =
                make_float4(acc[ee][0], acc[ee][1], acc[ee][2], acc[ee][3]);
            float ps = acc[ee][0]*as.x + acc[ee][1]*as.y + acc[ee][2]*as.z + acc[ee][3]*as.w;
            float pd = acc[ee][0]*ad.x + acc[ee][1]*ad.y + acc[ee][2]*ad.z + acc[ee][3]*ad.w;
#pragma unroll
            for (int mk = 1; mk < 8; mk <<= 1) {
                ps += __shfl_xor(ps, mk, 32);
                pd += __shfl_xor(pd, mk, 32);
            }
            if (((t & 31) & 7) == 0) {
                ssrc[r * HEADS + hh] = ps;
                sdst[r * HEADS + hh] = pd;
            }
        }
    }
}

// ---------------- layer kernels ----------------

// waE[k][h] = sum_c We[k][h*32+c] * att_edge[h*32+c]   (1 block, 128 threads)
__global__ void make_waE(const float* __restrict__ We, const float* __restrict__ att_e,
                         float* __restrict__ waE) {
    int k = threadIdx.x;
#pragma unroll
    for (int h = 0; h < HEADS; h++) {
        float s = 0.f;
#pragma unroll
        for (int c = 0; c < CH; c++) s += We[k * DIM + h * CH + c] * att_e[h * CH + c];
        waE[k * HEADS + h] = s;
    }
}

// lw[e,h] = leaky(ssrc[src,h] + sdst[dst,h] + e_row · waE[:,h]).  8 edges/block, 256 thr.
__global__ void sedge_logits(const float* __restrict__ e, const float* __restrict__ waE,
                             const float* __restrict__ ssrc, const float* __restrict__ sdst,
                             const int* __restrict__ src, const int* __restrict__ dst,
                             float* __restrict__ lw, int E) {
    __shared__ float w[DIM * HEADS];
    int t = threadIdx.x;
    w[t] = waE[t]; w[t + 256] = waE[t + 256];
    __syncthreads();
    int g = t >> 5, lane = t & 31;
    int eid = blockIdx.x * 8 + g;
    if (eid >= E) return;
    const float* er = e + (size_t)eid * DIM;
    float s0 = 0.f, s1 = 0.f, s2 = 0.f, s3 = 0.f;
#pragma unroll
    for (int j = 0; j < 4; j++) {
        int k = lane + 32 * j;
        float v = er[k];
        s0 += v * w[k * 4 + 0]; s1 += v * w[k * 4 + 1];
        s2 += v * w[k * 4 + 2]; s3 += v * w[k * 4 + 3];
    }
#pragma unroll
    for (int m = 16; m; m >>= 1) {
        s0 += __shfl_xor(s0, m, 32); s1 += __shfl_xor(s1, m, 32);
        s2 += __shfl_xor(s2, m, 32); s3 += __shfl_xor(s3, m, 32);
    }
    if (lane == 0) {
        int sn = src[eid] * HEADS, dn = dst[eid] * HEADS;
        float l0 = ssrc[sn + 0] + sdst[dn + 0] + s0;
        float l1 = ssrc[sn + 1] + sdst[dn + 1] + s1;
        float l2 = ssrc[sn + 2] + sdst[dn + 2] + s2;
        float l3 = ssrc[sn + 3] + sdst[dn + 3] + s3;
        lw[eid * 4 + 0] = (l0 >= 0.f) ? l0 : 0.2f * l0;
        lw[eid * 4 + 1] = (l1 >= 0.f) ? l1 : 0.2f * l1;
        lw[eid * 4 + 2] = (l2 >= 0.f) ? l2 : 0.2f * l2;
        lw[eid * 4 + 3] = (l3 >= 0.f) ? l3 : 0.2f * l3;
    }
}

// per (node, head) thread: segment max, exp, sum.
__global__ void seg_softmax(const int* __restrict__ off, const int* __restrict__ csr,
                            float* __restrict__ lw, float* __restrict__ den, int NH) {
    int i = blockIdx.x * blockDim.x + threadIdx.x;
    if (i >= NH) return;
    int n = i >> 2, hh = i & 3;
    int o0 = off[n], o1 = off[n + 1];
    float m = -1e30f;
    for (int o = o0; o < o1; o++) m = fmaxf(m, lw[csr[o] * HEADS + hh]);
    float s = 0.f;
    for (int o = o0; o < o1; o++) {
        int idx = csr[o] * HEADS + hh;
        float w = __expf(lw[idx] - m);
        lw[idx] = w;
        s += w;
    }
    den[i] = s;
}

// conv gather + We-transform of edge aggregate + LN1 + relu + residual. 1 node/block.
__global__ void conv_ln(const int* __restrict__ off, const int* __restrict__ csr,
                        const int* __restrict__ src,
                        const float* __restrict__ lw, const float* __restrict__ den,
                        const float* __restrict__ hbuf, const float* __restrict__ e,
                        const float* __restrict__ We,
                        const float* __restrict__ bn, const float* __restrict__ g,
                        const float* __restrict__ b, float* __restrict__ x, int N) {
    int n = blockIdx.x, t = threadIdx.x, hh = t >> 5;
    __shared__ float agge[HEADS][DIM];
    __shared__ float red[DIM];
    int o0 = off[n], o1 = off[n + 1];
    float acch = 0.f, a0 = 0.f, a1 = 0.f, a2 = 0.f, a3 = 0.f;
    for (int o = o0; o < o1; o++) {
        int eid = csr[o];
        int s = src[eid];
        float4 al = *(const float4*)&lw[eid * 4];
        acch += ((&al.x)[hh]) * hbuf[(size_t)s * DIM + t];
        float ev = e[(size_t)eid * DIM + t];
        a0 += al.x * ev; a1 += al.y * ev; a2 += al.z * ev; a3 += al.w * ev;
    }
    agge[0][t] = a0; agge[1][t] = a1; agge[2][t] = a2; agge[3][t] = a3;
    __syncthreads();
    float ehc = 0.f;
#pragma unroll 8
    for (int k = 0; k < DIM; k++) ehc += agge[hh][k] * We[k * DIM + t];
    float d = den[n * HEADS + hh];
    float conv = (acch + ehc) / (d + 1e-16f) + bn[t];
    float mu = block_reduce_sum128(conv, red) * (1.f / DIM);
    float diff = conv - mu;
    float var = block_reduce_sum128(diff * diff, red) * (1.f / DIM);
    float y = diff * rsqrtf(var + 1e-5f) * g[t] + b[t];
    x[(size_t)n * DIM + t] = fmaxf(y, 0.f) + x[(size_t)n * DIM + t];
}

// k = memory @ Wk, v = memory @ Wv. 1 row/block.
__global__ void kv_proj(const float* __restrict__ mem, const float* __restrict__ Wk,
                        const float* __restrict__ Wv, float* __restrict__ kb,
                        float* __restrict__ vb, int R) {
    int r = blockIdx.x, t = threadIdx.x;
    __shared__ float row[DIM];
    row[t] = mem[(size_t)r * DIM + t];
    __syncthreads();
    float ak = 0.f, av = 0.f;
#pragma unroll 4
    for (int k = 0; k < DIM; k++) {
        float rv = row[k];
        ak += rv * Wk[k * DIM + t];
        av += rv * Wv[k * DIM + t];
    }
    kb[(size_t)r * DIM + t] = ak;
    vb[(size_t)r * DIM + t] = av;
}

// flash-style cross attention: 64 queries x 1 batch per block, 256 thr = 64q x 4h.
// qg precomputed (x@Wq). K/V staged in LDS in 32-key chunks, online softmax in regs.
// Epilogue: ao@Wo + residual + LN2 + relu, in-place on x.
__global__ __launch_bounds__(256) void cross_attn_tile(
    float* __restrict__ x, const float* __restrict__ qg,
    const float* __restrict__ kb, const float* __restrict__ vb,
    const float* __restrict__ Wo, const float* __restrict__ g,
    const float* __restrict__ b, const int* __restrict__ boff) {
    int bb = blockIdx.y;
    int n0 = boff[bb] + blockIdx.x * 64;
    int cnt = boff[bb + 1] - n0;
    if (cnt <= 0) return;
    int nq = min(64, cnt);
    int t = threadIdx.x;
    int q = t & 63, h = t >> 6;

    __shared__ float smem[64 * 132];  // phase A: K[32][128] | V[32][128]; phase B: ao[64][132]

    float qv[32];
    if (q < nq) {
        const float4* qp = (const float4*)(qg + (size_t)(n0 + q) * DIM + h * CH);
#pragma unroll
        for (int j = 0; j < 8; j++) {
            float4 v = qp[j];
            qv[4*j+0] = v.x; qv[4*j+1] = v.y; qv[4*j+2] = v.z; qv[4*j+3] = v.w;
        }
    } else {
#pragma unroll
        for (int c = 0; c < 32; c++) qv[c] = 0.f;
    }

    float oacc[32];
#pragma unroll
    for (int c = 0; c < 32; c++) oacc[c] = 0.f;
    float m = -1e30f, l = 0.f;

    const float4* Ksrc = (const float4*)(kb + (size_t)bb * MEMLEN * DIM);
    const float4* Vsrc = (const float4*)(vb + (size_t)bb * MEMLEN * DIM);
    float4* Kl = (float4*)smem;
    float4* Vl = (float4*)(smem + 32 * DIM);

    for (int ch = 0; ch < MEMLEN / 32; ch++) {
        __syncthreads();
#pragma unroll
        for (int r = 0; r < 4; r++) {
            int idx = t + r * 256;
            Kl[idx] = Ksrc[ch * 1024 + idx];
            Vl[idx] = Vsrc[ch * 1024 + idx];
        }
        __syncthreads();
        float sc[32];
#pragma unroll
        for (int kk = 0; kk < 32; kk++) {
            const float* kp = smem + kk * DIM + h * CH;
            float s = 0.f;
#pragma unroll
            for (int c = 0; c < 32; c++) s += qv[c] * kp[c];
            sc[kk] = s * 0.17677669529663689f;
        }
        float mc = sc[0];
#pragma unroll
        for (int kk = 1; kk < 32; kk++) mc = fmaxf(mc, sc[kk]);
        float mn = fmaxf(m, mc);
        float scale = __expf(m - mn);
        m = mn;
        float ls = 0.f;
#pragma unroll
        for (int kk = 0; kk < 32; kk++) {
            float w = __expf(sc[kk] - mn);
            sc[kk] = w;
            ls += w;
        }
        l = l * scale + ls;
#pragma unroll
        for (int c = 0; c < 32; c++) oacc[c] *= scale;
#pragma unroll
        for (int kk = 0; kk < 32; kk++) {
            const float* vp = smem + 32 * DIM + kk * DIM + h * CH;
            float w = sc[kk];
#pragma unroll
            for (int c = 0; c < 32; c++) oacc[c] += w * vp[c];
        }
    }
    __syncthreads();
    // phase B: ao into padded LDS [64][132]
    {
        float inv = 1.f / l;
        float* ap = smem + q * 132 + h * CH;
#pragma unroll
        for (int c = 0; c < 32; c++) ap[c] = oacc[c] * inv;
    }
    __syncthreads();
    // Wo GEMM (8 rows x 4 cols per thread) + residual + LN + relu
    int c0 = (t & 31) * 4;
    int rb = (t >> 5) * 8;
    float acc2[8][4];
#pragma unroll
    for (int ee = 0; ee < 8; ee++)
        acc2[ee][0] = acc2[ee][1] = acc2[ee][2] = acc2[ee][3] = 0.f;
    for (int k = 0; k < DIM; k += 4) {
        float4 w0 = *(const float4*)&Wo[(k + 0) * DIM + c0];
        float4 w1 = *(const float4*)&Wo[(k + 1) * DIM + c0];
        float4 w2 = *(const float4*)&Wo[(k + 2) * DIM + c0];
        float4 w3 = *(const float4*)&Wo[(k + 3) * DIM + c0];
#pragma unroll
        for (int ee = 0; ee < 8; ee++) {
            float4 a = *(const float4*)(smem + (rb + ee) * 132 + k);
            acc2[ee][0] += a.x * w0.x + a.y * w1.x + a.z * w2.x + a.w * w3.x;
            acc2[ee][1] += a.x * w0.y + a.y * w1.y + a.z * w2.y + a.w * w3.y;
            acc2[ee][2] += a.x * w0.z + a.y * w1.z + a.z * w2.z + a.w * w3.z;
            acc2[ee][3] += a.x * w0.w + a.y * w1.w + a.z * w2.w + a.w * w3.w;
        }
    }
    float4 gg = *(const float4*)&g[c0];
    float4 bb4 = *(const float4*)&b[c0];
#pragma unroll
    for (int ee = 0; ee < 8; ee++) {
        int r = rb + ee;
        if (r < nq) {
            float4 xr = *(const float4*)&x[(size_t)(n0 + r) * DIM + c0];
            float o0 = acc2[ee][0] + xr.x, o1 = acc2[ee][1] + xr.y;
            float o2 = acc2[ee][2] + xr.z, o3 = acc2[ee][3] + xr.w;
            float s1 = o0 + o1 + o2 + o3;
#pragma unroll
            for (int mk = 16; mk; mk >>= 1) s1 += __shfl_xor(s1, mk, 32);
            float mu = s1 * (1.f / DIM);
            float d0 = o0 - mu, d1 = o1 - mu, d2 = o2 - mu, d3 = o3 - mu;
            float s2 = d0*d0 + d1*d1 + d2*d2 + d3*d3;
#pragma unroll
            for (int mk = 16; mk; mk >>= 1) s2 += __shfl_xor(s2, mk, 32);
            float rs = rsqrtf(s2 * (1.f / DIM) + 1e-5f);
            float4 o = make_float4(fmaxf(d0 * rs * gg.x + bb4.x, 0.f),
                                   fmaxf(d1 * rs * gg.y + bb4.y, 0.f),
                                   fmaxf(d2 * rs * gg.z + bb4.z, 0.f),
                                   fmaxf(d3 * rs * gg.w + bb4.w, 0.f));
            *(float4*)&x[(size_t)(n0 + r) * DIM + c0] = o;
        }
    }
}

// hid = relu(e@W1 + xs[src] + xd[dst]); e += hid@W2 + Eb2.  64 edges/block, 256 thr.
__global__ __launch_bounds__(256) void edge_mlp(float* __restrict__ e,
                                                const float* __restrict__ xs,
                                                const float* __restrict__ xd,
                                                const int* __restrict__ src,
                                                const int* __restrict__ dst,
                                                const float* __restrict__ W1,
                                                const float* __restrict__ W2,
                                                const float* __restrict__ Eb2, int E) {
    int e0 = blockIdx.x * 64, t = threadIdx.x;
    __shared__ float at[64][DIM];
    for (int i = t; i < 64 * 32; i += 256) {
        int rr = i >> 5, cc = i & 31;
        if (e0 + rr < E)
            ((float4*)at[rr])[cc] = ((const float4*)(e + (size_t)(e0 + rr) * DIM))[cc];
    }
    __syncthreads();
    int c0 = (t & 31) * 4;
    int rb = (t >> 5) * 8;
    float acc[8][4];
#pragma unroll
    for (int ee = 0; ee < 8; ee++)
        acc[ee][0] = acc[ee][1] = acc[ee][2] = acc[ee][3] = 0.f;
    for (int k = 0; k < DIM; k += 4) {
        float4 w0 = *(const float4*)&W1[(k + 0) * DIM + c0];
        float4 w1 = *(const float4*)&W1[(k + 1) * DIM + c0];
        float4 w2 = *(const float4*)&W1[(k + 2) * DIM + c0];
        float4 w3 = *(const float4*)&W1[(k + 3) * DIM + c0];
#pragma unroll
        for (int ee = 0; ee < 8; ee++) {
            float4 a = *(float4*)&at[rb + ee][k];
            acc[ee][0] += a.x * w0.x + a.y * w1.x + a.z * w2.x + a.w * w3.x;
            acc[ee][1] += a.x * w0.y + a.y * w1.y + a.z * w2.y + a.w * w3.y;
            acc[ee][2] += a.x * w0.z + a.y * w1.z + a.z * w2.z + a.w * w3.z;
            acc[ee][3] += a.x * w0.w + a.y * w1.w + a.z * w2.w + a.w * w3.w;
        }
    }
#pragma unroll
    for (int ee = 0; ee < 8; ee++) {
        int r = e0 + rb + ee;
        if (r < E) {
            float4 s4 = *(const float4*)&xs[(size_t)src[r] * DIM + c0];
            float4 d4 = *(const float4*)&xd[(size_t)dst[r] * DIM + c0];
            acc[ee][0] = fmaxf(acc[ee][0] + s4.x + d4.x, 0.f);
            acc[ee][1] = fmaxf(acc[ee][1] + s4.y + d4.y, 0.f);
            acc[ee][2] = fmaxf(acc[ee][2] + s4.z + d4.z, 0.f);
            acc[ee][3] = fmaxf(acc[ee][3] + s4.w + d4.w, 0.f);
        }
    }
    __syncthreads();
#pragma unroll
    for (int ee = 0; ee < 8; ee++)
        *(float4*)&at[rb + ee][c0] = make_float4(acc[ee][0], acc[ee][1], acc[ee][2], acc[ee][3]);
    __syncthreads();
#pragma unroll
    for (int ee = 0; ee < 8; ee++)
        acc[ee][0] = acc[ee][1] = acc[ee][2] = acc[ee][3] = 0.f;
    for (int k = 0; k < DIM; k += 4) {
        float4 w0 = *(const float4*)&W2[(k + 0) * DIM + c0];
        float4 w1 = *(const float4*)&W2[(k + 1) * DIM + c0];
        float4 w2 = *(const float4*)&W2[(k + 2) * DIM + c0];
        float4 w3 = *(const float4*)&W2[(k + 3) * DIM + c0];
#pragma unroll
        for (int ee = 0; ee < 8; ee++) {
            float4 a = *(float4*)&at[rb + ee][k];
            acc[ee][0] += a.x * w0.x + a.y * w1.x + a.z * w2.x + a.w * w3.x;
            acc[ee][1] += a.x * w0.y + a.y * w1.y + a.z * w2.y + a.w * w3.y;
            acc[ee][2] += a.x * w0.z + a.y * w1.z + a.z * w2.z + a.w * w3.z;
            acc[ee][3] += a.x * w0.w + a.y * w1.w + a.z * w2.w + a.w * w3.w;
        }
    }
    float4 b2 = *(const float4*)&Eb2[c0];
#pragma unroll
    for (int ee = 0; ee < 8; ee++) {
        int r = e0 + rb + ee;
        if (r < E) {
            float4 old = *(const float4*)&e[(size_t)r * DIM + c0];
            float4 o = make_float4(old.x + acc[ee][0] + b2.x, old.y + acc[ee][1] + b2.y,
                                   old.z + acc[ee][2] + b2.z, old.w + acc[ee][3] + b2.w);
            *(float4*)&e[(size_t)r * DIM + c0] = o;
        }
    }
}

// ---------------- driver ----------------

extern "C" void kernel_launch(void* const* d_in, const int* in_sizes, int n_in,
                              void* d_out, int out_size, void* d_ws, size_t ws_size,
                              hipStream_t stream) {
    const float* node_feats = (const float*)d_in[0];
    const float* edge_feats = (const float*)d_in[1];
    const float* memory     = (const float*)d_in[2];
    const float* Wn   = (const float*)d_in[3];
    const float* bn   = (const float*)d_in[4];
    const float* We   = (const float*)d_in[5];
    const float* att_src  = (const float*)d_in[6];
    const float* att_dst  = (const float*)d_in[7];
    const float* att_edge = (const float*)d_in[8];
    const float* ln1_g = (const float*)d_in[9];
    const float* ln1_b = (const float*)d_in[10];
    const float* ln2_g = (const float*)d_in[11];
    const float* ln2_b = (const float*)d_in[12];
    const float* Wq = (const float*)d_in[13];
    const float* Wk = (const float*)d_in[14];
    const float* Wv = (const float*)d_in[15];
    const float* Wo = (const float*)d_in[16];
    const float* Ew1 = (const float*)d_in[17];
    const float* Eb1 = (const float*)d_in[18];
    const float* Ew2 = (const float*)d_in[19];
    const float* Eb2 = (const float*)d_in[20];
    const int* edge_index = (const int*)d_in[21];
    const int* node2batch = (const int*)d_in[22];

    const int N = in_sizes[0] / DIM;
    const int E = in_sizes[1] / DIM;
    const int Bn = in_sizes[2] / (MEMLEN * DIM);
    const int* srcA = edge_index;
    const int* dstA = edge_index + E;

    float* x = (float*)d_out;
    float* e = x + (size_t)N * DIM;

    // workspace carve
    char* p = (char*)d_ws;
    auto carve = [&](size_t bytes) {
        void* r = (void*)p;
        p += (bytes + 255) & ~(size_t)255;
        return r;
    };
    float* h     = (float*)carve((size_t)N * DIM * 4);
    float* qg    = (float*)carve((size_t)N * DIM * 4);
    float* xs    = (float*)carve((size_t)N * DIM * 4);
    float* xd    = (float*)carve((size_t)N * DIM * 4);
    float* ssrc  = (float*)carve((size_t)N * HEADS * 4);
    float* sdst  = (float*)carve((size_t)N * HEADS * 4);
    float* lw    = (float*)carve((size_t)E * HEADS * 4);
    float* den   = (float*)carve((size_t)N * HEADS * 4);
    float* waE   = (float*)carve((size_t)DIM * HEADS * 4);
    float* kbuf  = (float*)carve((size_t)Bn * MEMLEN * DIM * 4);
    float* vbuf  = (float*)carve((size_t)Bn * MEMLEN * DIM * 4);
    int* deg     = (int*)carve((size_t)N * 4);
    int* cur     = (int*)carve((size_t)N * 4);
    int* off     = (int*)carve(((size_t)N + 1) * 4);
    int* csr     = (int*)carve((size_t)E * 4);
    int* bcnt    = (int*)carve((size_t)Bn * 4);
    int* boff    = (int*)carve(((size_t)Bn + 1) * 4);

    // init outputs from inputs
    {
        long nx = (long)N * DIM / 4;
        copy_f4<<<dim3(2048), dim3(256), 0, stream>>>((const float4*)node_feats, (float4*)x, nx);
        long nen = (long)E * DIM / 4;
        copy_f4<<<dim3(4096), dim3(256), 0, stream>>>((const float4*)edge_feats, (float4*)e, nen);
    }

    // CSR over dst + per-batch node offsets
    hipMemsetAsync(deg, 0, (size_t)N * 4, stream);
    hipMemsetAsync(cur, 0, (size_t)N * 4, stream);
    hipMemsetAsync(bcnt, 0, (size_t)Bn * 4, stream);
    hist_k<<<dim3((E + 255) / 256), dim3(256), 0, stream>>>(dstA, E, deg);
    csr_offsets<<<dim3(1), dim3(1024), 0, stream>>>(deg, N, off);
    csr_fill<<<dim3((E + 255) / 256), dim3(256), 0, stream>>>(dstA, E, off, cur, csr);
    hist_k<<<dim3((N + 255) / 256), dim3(256), 0, stream>>>(node2batch, N, bcnt);
    csr_offsets<<<dim3(1), dim3(1024), 0, stream>>>(bcnt, Bn, boff);

    const int mrows = Bn * MEMLEN;
    const int maxTiles = 1024 / 64;  // MAX_NODE / 64
    for (int l = 0; l < LAYERS; l++) {
        const float* Wn_l  = Wn  + (size_t)l * DIM * DIM;
        const float* We_l  = We  + (size_t)l * DIM * DIM;
        const float* Wq_l  = Wq  + (size_t)l * DIM * DIM;
        const float* Wk_l  = Wk  + (size_t)l * DIM * DIM;
        const float* Wv_l  = Wv  + (size_t)l * DIM * DIM;
        const float* Wo_l  = Wo  + (size_t)l * DIM * DIM;
        const float* Ew1_l = Ew1 + (size_t)l * 3 * DIM * DIM;
        const float* Ew2_l = Ew2 + (size_t)l * DIM * DIM;

        node_proj_tile<<<dim3((N + 63) / 64), dim3(256), 0, stream>>>(
            x, Wn_l, att_src + l * DIM, att_dst + l * DIM, h, ssrc, sdst, N);
        make_waE<<<dim3(1), dim3(DIM), 0, stream>>>(We_l, att_edge + l * DIM, waE);
        sedge_logits<<<dim3((E + 7) / 8), dim3(256), 0, stream>>>(
            e, waE, ssrc, sdst, srcA, dstA, lw, E);
        seg_softmax<<<dim3((N * HEADS + 255) / 256), dim3(256), 0, stream>>>(
            off, csr, lw, den, N * HEADS);
        conv_ln<<<dim3(N), dim3(DIM), 0, stream>>>(
            off, csr, srcA, lw, den, h, e, We_l,
            bn + l * DIM, ln1_g + l * DIM, ln1_b + l * DIM, x, N);
        kv_proj<<<dim3(mrows), dim3(DIM), 0, stream>>>(
            memory, Wk_l, Wv_l, kbuf, vbuf, mrows);
        gemm128<<<dim3((N + 63) / 64), dim3(256), 0, stream>>>(
            x, Wq_l, nullptr, qg, N);
        cross_attn_tile<<<dim3(maxTiles, Bn), dim3(256), 0, stream>>>(
            x, qg, kbuf, vbuf, Wo_l, ln2_g + l * DIM, ln2_b + l * DIM, boff);
        gemm128<<<dim3((N + 63) / 64), dim3(256), 0, stream>>>(
            x, Ew1_l + (size_t)DIM * DIM, Eb1 + l * DIM, xs, N);
        gemm128<<<dim3((N + 63) / 64), dim3(256), 0, stream>>>(
            x, Ew1_l + (size_t)2 * DIM * DIM, nullptr, xd, N);
        edge_mlp<<<dim3((E + 63) / 64), dim3(256), 0, stream>>>(
            e, xs, xd, srcA, dstA, Ew1_l, Ew2_l, Eb2 + l * DIM, E);
    }
}